// Round 9
// baseline (172.351 us; speedup 1.0000x reference)
//
#include <hip/hip_runtime.h>

// LocalizationLoss: B=1048576, N=3, C=7. output (B,3,7) fp32, target (B,3,5) fp32.
// result = (5*(Sx+Sy+2*Swh) + 3*Sce - 0.5*Sbce)/(B*N) + 0.5   (scalar fp32)
//
// R1: per-block partials (77->59us).
// R2/R3/R5: LDS staging variants, 58-62us.
// R6: stage-after-compute rotation + NT: kernel ~45us (below the 53us fills).
// R7: depth-2 rotation: neutral (~48us) -> latency is covered; the
//     global_load_lds path itself caps at ~3.4 TB/s demand while the
//     harness fill kernel does 6.7 TB/s. Suspect per-CU LDS-DMA
//     outstanding-fill cap (Q*64B/latency ~ few B/cyc/CU).
// R8 (discriminator; the cell R4 botched with a 512-block grid + spills):
//     NO LDS, NO global_load_lds. 1 row/thread, 1M threads, 32 waves/CU,
//     11 direct register loads per lane, compute inline, wave reduce.
//     In-flight: 32 waves x ~9KB >> BW*latency (~20KB/CU). If this hits
//     ~25-32us the DMA cap theory stands; if ~45-60us with no spills,
//     the demand ceiling is path-independent -> roofline.

#define NBLK 4096            // 4096 blocks x 256 threads x 1 row = B
#define INV_BN (1.0f / 3145728.0f)

typedef float f4u __attribute__((ext_vector_type(4), aligned(4)));
typedef float f2u __attribute__((ext_vector_type(2), aligned(4)));

__global__ __launch_bounds__(256, 8) void loc_loss_kernel(
    const float* __restrict__ gout, const float* __restrict__ gtgt,
    float* __restrict__ ws) {
  const int tid = threadIdx.x;
  const size_t g = (size_t)blockIdx.x * 256 + tid;
  const float* op = gout + g * 21;
  const float* tp = gtgt + g * 15;

  // Issue all 11 loads back-to-back (per-lane rows are 4B-aligned; dwordx4
  // needs only dword alignment). ~36 live VGPRs of data.
  const f4u o0 = *(const f4u*)(op + 0);
  const f4u o1 = *(const f4u*)(op + 4);
  const f4u o2 = *(const f4u*)(op + 8);
  const f4u o3 = *(const f4u*)(op + 12);
  const f4u o4 = *(const f4u*)(op + 16);
  const float o20 = op[20];
  const f4u t0 = *(const f4u*)(tp + 0);
  const f4u t1 = *(const f4u*)(tp + 4);
  const f4u t2 = *(const f4u*)(tp + 8);
  const f2u t12 = *(const f2u*)(tp + 12);
  const float t14 = tp[14];

  float o[21], t[15];
  o[0]=o0.x;  o[1]=o0.y;  o[2]=o0.z;  o[3]=o0.w;
  o[4]=o1.x;  o[5]=o1.y;  o[6]=o1.z;  o[7]=o1.w;
  o[8]=o2.x;  o[9]=o2.y;  o[10]=o2.z; o[11]=o2.w;
  o[12]=o3.x; o[13]=o3.y; o[14]=o3.z; o[15]=o3.w;
  o[16]=o4.x; o[17]=o4.y; o[18]=o4.z; o[19]=o4.w;
  o[20]=o20;
  t[0]=t0.x;  t[1]=t0.y;  t[2]=t0.z;  t[3]=t0.w;
  t[4]=t1.x;  t[5]=t1.y;  t[6]=t1.z;  t[7]=t1.w;
  t[8]=t2.x;  t[9]=t2.y;  t[10]=t2.z; t[11]=t2.w;
  t[12]=t12.x; t[13]=t12.y; t[14]=t14;

  float pbce = 1.f, sx = 0.f, sy = 0.f, swh = 0.f, sel = 0.f;
  float Lg[3][3];
  int cls[3];
  #pragma unroll
  for (int n = 0; n < 3; ++n) {
    const float tt = t[n * 5 + 0];
    const bool mk = (tt != 0.f);
    const float m = mk ? 1.f : 0.f;
    const float p = o[n * 7 + 0];
    pbce *= mk ? p : 1.f - p;               // 3 logs -> 1
    const float dx = o[n * 7 + 1] * m - t[n * 5 + 1];
    sx += dx * dx;
    const float dy = o[n * 7 + 2] * m - t[n * 5 + 2];
    sy += dy * dy;
    const float o3f = o[n * 7 + 3], t3f = t[n * 5 + 3];
    // masked: (sqrt(o)-sqrt(t))^2 = o + t - 2*sqrt(o*t); unmasked: t
    swh += t3f + (mk ? (o3f - 2.f * __builtin_sqrtf(o3f * t3f)) : 0.f);
    Lg[n][0] = o[n * 7 + 4] * m;
    Lg[n][1] = o[n * 7 + 5] * m;
    Lg[n][2] = o[n * 7 + 6] * m;
    cls[n] = (int)t[n * 5 + 4];
  }
  float prodS = 1.f;
  #pragma unroll
  for (int j = 0; j < 3; ++j) {
    // masked logits in [0,1]; per-channel denominator in [3,3e] -> prod <= ~550
    prodS *= __expf(Lg[0][j]) + __expf(Lg[1][j]) + __expf(Lg[2][j]);
    const int idx = cls[j];
    sel += (idx == 0) ? Lg[0][j] : ((idx == 1) ? Lg[1][j] : Lg[2][j]);
  }
  float acc = 5.f * (sx + sy + 2.f * swh) + 3.f * (__logf(prodS) - sel)
              - 0.5f * __logf(pbce);

  // wave reduce -> one partial per wave (16384 total)
  #pragma unroll
  for (int off = 32; off > 0; off >>= 1) acc += __shfl_down(acc, off, 64);
  if ((tid & 63) == 0) ws[(size_t)blockIdx.x * 4 + (tid >> 6)] = acc;
}

__global__ __launch_bounds__(256) void loc_loss_finalize(
    const float* __restrict__ ws, float* __restrict__ out) {
  __shared__ float s_wave[4];
  const int tid = threadIdx.x;
  const float4* w4 = (const float4*)ws;  // 16384 partials = 4096 float4
  float acc = 0.f;
  #pragma unroll
  for (int i = 0; i < 16; ++i) {
    float4 v = w4[tid + 256 * i];
    acc += (v.x + v.y) + (v.z + v.w);
  }
  #pragma unroll
  for (int off = 32; off > 0; off >>= 1) acc += __shfl_down(acc, off, 64);
  if ((tid & 63) == 0) s_wave[tid >> 6] = acc;
  __syncthreads();
  if (tid == 0) {
    out[0] = (s_wave[0] + s_wave[1] + s_wave[2] + s_wave[3]) * INV_BN + 0.5f;
  }
}

extern "C" void kernel_launch(void* const* d_in, const int* in_sizes, int n_in,
                              void* d_out, int out_size, void* d_ws, size_t ws_size,
                              hipStream_t stream) {
  const float* gout = (const float*)d_in[0];  // (B,3,7)
  const float* gtgt = (const float*)d_in[1];  // (B,3,5)
  float* ws = (float*)d_ws;                   // 16384 floats = 64 KB
  float* out = (float*)d_out;

  loc_loss_kernel<<<NBLK, 256, 0, stream>>>(gout, gtgt, ws);
  loc_loss_finalize<<<1, 256, 0, stream>>>(ws, out);
}